// Round 7
// baseline (340.175 us; speedup 1.0000x reference)
//
#include <hip/hip_runtime.h>

// Siddon forward projection, round 7: PIXEL-DRIVEN (parallel-beam), with
// exact per-view geometry (fp64 setup, detector spacing == 1 by construction).
// Each pixel's contribution to a ray is the chord length of its unit square
// at perpendicular offset delta — a closed-form trapezoid with support
// <= sqrt(2) < 2 det spacings -> at most 2 detectors per pixel.
// Workgroup = (view, 16-line band); 4ch x 384 detector profile in LDS via
// atomicAdd; band partials reduced by a second kernel.
//
// inputs: image[4][256][256] f32, tvals (UNUSED), M[2][2] (=I), b[2],
//         src[69120][2], dst[69120][2]
// output: sinogram[4][69120] f32

#define N_ROW  256
#define N_COL  256
#define N_VIEW 180
#define N_DET  384
#define N_RAY  69120
#define IMG_PIX (N_ROW * N_COL)
#define NBAND  16
#define BANDH  (N_ROW / NBAND)     // 16
#define PROF   (4 * N_DET)         // 1536 floats per partial profile
#define WS_IMG   (2u * IMG_PIX * 16u)                     // 2 MiB float4 x2
#define WS_PART  ((unsigned)(N_VIEW * NBAND * PROF) * 4u) // ~17.7 MiB
#define WS_NEEDED (WS_IMG + WS_PART)

__global__ __launch_bounds__(256) void ct_prep_kernel(
    const float* __restrict__ image,
    float4* __restrict__ img_rc,   // [r*256 + c] -> (ch0..ch3), c fastest
    float4* __restrict__ img_cr)   // [c*256 + r] -> (ch0..ch3), r fastest
{
    const int p = blockIdx.x * blockDim.x + threadIdx.x;
    if (p >= IMG_PIX) return;
    const int r = p >> 8;
    const int c = p & 255;
    float4 v;
    v.x = image[0 * IMG_PIX + p];
    v.y = image[1 * IMG_PIX + p];
    v.z = image[2 * IMG_PIX + p];
    v.w = image[3 * IMG_PIX + p];
    img_rc[p] = v;
    img_cr[(c << 8) | r] = v;
}

__global__ __launch_bounds__(256) void ct_px_kernel(
    const float4* __restrict__ img_rc,
    const float4* __restrict__ img_cr,
    const float* __restrict__ bb,
    const float* __restrict__ src,
    const float* __restrict__ dst,
    float* __restrict__ part)      // [N_VIEW*NBAND][PROF], layout [ch][det]
{
    __shared__ float sino[PROF];

    const int wg   = blockIdx.x;
    const int v    = wg >> 4;          // / NBAND
    const int band = wg & (NBAND - 1);
    const int tid  = threadIdx.x;

    for (int i = tid; i < PROF; i += 256) sino[i] = 0.0f;

    // ---- per-view geometry, fp64, workgroup-uniform ----
    const int r0 = v * N_DET;
    const double sx0 = (double)src[2 * r0 + 0], sy0 = (double)src[2 * r0 + 1];
    const double ex0 = (double)dst[2 * r0 + 0], ey0 = (double)dst[2 * r0 + 1];
    double gxd = ex0 - sx0, gyd = ey0 - sy0;
    const double gl = sqrt(gxd * gxd + gyd * gyd);
    gxd /= gl; gyd /= gl;                       // unit ray direction
    const double pxd = -gyd, pyd = gxd;         // unit perpendicular
    const double off0d = sx0 * pxd + sy0 * pyd; // detector-0 offset
    const double off1d = (double)src[2 * (r0 + 1) + 0] * pxd
                       + (double)src[2 * (r0 + 1) + 1] * pyd;
    // detector spacing is EXACTLY 1 world unit by construction; only the
    // sign (perp orientation vs detector numbering) is taken from the data.
    const double sgn = (off1d > off0d) ? 1.0 : -1.0;

    const float pxs  = (float)(pxd * sgn);
    const float pys  = (float)(pyd * sgn);
    const float offs = (float)(off0d * sgn);

    const float a  = (float)fabs(gxd), b2 = (float)fabs(gyd);
    const float outer  = 0.5f * (a + b2);          // support half-width
    const float peak   = 1.0f / fmaxf(a, b2);      // plateau chord length
    const float inv_ab = 1.0f / fmaxf(a * b2, 1e-20f);

    const float bx = bb[0], by = bb[1];

    // fast axis = axis with larger |d kf| per step: |dkf/dc| = |pys| = a,
    // |dkf/dr| = |pxs| = b2.  (>= 0.707 -> adjacent lanes hit distinct dets)
    const bool cfast = (a >= b2);
    const float4* __restrict__ img = cfast ? img_rc : img_cr;

    __syncthreads();

    const int fast = tid;
    #pragma unroll 1
    for (int it = 0; it < BANDH; ++it) {
        const int slow = band * BANDH + it;
        const int r = cfast ? slow : fast;
        const int c = cfast ? fast : slow;
        const float wxp = (float)r + bx;         // world x of pixel center
        const float wyp = (float)c + by;         // world y
        // fractional detector index (spacing exactly 1)
        const float kf = fmaf(wxp, pxs, fmaf(wyp, pys, -offs));

        const float kaf = ceilf(kf - outer);
        const float d0  = kf - kaf;
        const float w0  = fminf(fmaxf((outer - fabsf(d0))        * inv_ab, 0.0f), peak);
        const float w1  = fminf(fmaxf((outer - fabsf(d0 - 1.0f)) * inv_ab, 0.0f), peak);
        const int k0 = (int)kaf;
        const int k1 = k0 + 1;

        const float4 vv = img[(slow << 8) | fast];   // coalesced 1KB/wave

        if (w0 > 0.0f && (unsigned)k0 < (unsigned)N_DET) {
            atomicAdd(&sino[0 * N_DET + k0], w0 * vv.x);
            atomicAdd(&sino[1 * N_DET + k0], w0 * vv.y);
            atomicAdd(&sino[2 * N_DET + k0], w0 * vv.z);
            atomicAdd(&sino[3 * N_DET + k0], w0 * vv.w);
        }
        if (w1 > 0.0f && (unsigned)k1 < (unsigned)N_DET) {
            atomicAdd(&sino[0 * N_DET + k1], w1 * vv.x);
            atomicAdd(&sino[1 * N_DET + k1], w1 * vv.y);
            atomicAdd(&sino[2 * N_DET + k1], w1 * vv.z);
            atomicAdd(&sino[3 * N_DET + k1], w1 * vv.w);
        }
    }

    __syncthreads();

    float* __restrict__ dp = part + (long)wg * PROF;
    for (int i = tid; i < PROF; i += 256) dp[i] = sino[i];
}

__global__ __launch_bounds__(384) void ct_reduce_kernel(
    const float* __restrict__ part,
    float* __restrict__ out)
{
    const int v  = blockIdx.x;       // 0..179
    const int ch = blockIdx.y;       // 0..3
    const int k  = threadIdx.x;      // 0..383
    float s = 0.0f;
    #pragma unroll
    for (int b = 0; b < NBAND; ++b)
        s += part[(long)(v * NBAND + b) * PROF + ch * N_DET + k];
    out[ch * N_RAY + v * N_DET + k] = s;
}

// ---- legacy fallback (round-1 kernel) if ws is too small ----
__global__ __launch_bounds__(256) void ct_fwd_legacy(
    const float* __restrict__ image,
    const float* __restrict__ tvals,
    const float* __restrict__ Mm,
    const float* __restrict__ bb,
    const float* __restrict__ src,
    const float* __restrict__ dst,
    float* __restrict__ out)
{
    const int wave = (blockIdx.x * blockDim.x + threadIdx.x) >> 6;
    const int lane = threadIdx.x & 63;
    if (wave >= N_RAY) return;
    const int ray = wave;

    const float m00 = Mm[0], m01 = Mm[1], m10 = Mm[2], m11 = Mm[3];
    const float invdet = 1.0f / (m00 * m11 - m01 * m10);
    const float i00 =  m11 * invdet, i01 = -m01 * invdet;
    const float i10 = -m10 * invdet, i11 =  m00 * invdet;

    const float sx = src[ray * 2 + 0], sy = src[ray * 2 + 1];
    const float ex = dst[ray * 2 + 0], ey = dst[ray * 2 + 1];
    const float bx = bb[0], by = bb[1];

    const float p0x = i00 * (sx - bx) + i01 * (sy - by);
    const float p0y = i10 * (sx - bx) + i11 * (sy - by);
    const float wdx = ex - sx, wdy = ey - sy;
    const float dx = i00 * wdx + i01 * wdy;
    const float dy = i10 * wdx + i11 * wdy;
    const float ray_len = sqrtf(wdx * wdx + wdy * wdy);

    const float* __restrict__ tv  = tvals + (long)ray * 514;
    const float* __restrict__ im0 = image;
    const float* __restrict__ im1 = image + 1 * IMG_PIX;
    const float* __restrict__ im2 = image + 2 * IMG_PIX;
    const float* __restrict__ im3 = image + 3 * IMG_PIX;

    float acc0 = 0.f, acc1 = 0.f, acc2 = 0.f, acc3 = 0.f;

    #pragma unroll
    for (int i = 0; i < 9; ++i) {
        const int s = i * 64 + lane;
        if (s < 513) {
            const float t0 = tv[s];
            const float t1 = tv[s + 1];
            const float dt = t1 - t0;
            if (dt > 0.f) {
                const float tm = 0.5f * (t0 + t1);
                const float ux = fmaf(tm, dx, p0x);
                const float uy = fmaf(tm, dy, p0y);
                const float rf = floorf(ux + 0.5f);
                const float cf = floorf(uy + 0.5f);
                if (rf >= 0.f && rf < (float)N_ROW && cf >= 0.f && cf < (float)N_COL) {
                    const int idx = (int)rf * N_COL + (int)cf;
                    const float w = dt * ray_len;
                    acc0 = fmaf(w, im0[idx], acc0);
                    acc1 = fmaf(w, im1[idx], acc1);
                    acc2 = fmaf(w, im2[idx], acc2);
                    acc3 = fmaf(w, im3[idx], acc3);
                }
            }
        }
    }

    #pragma unroll
    for (int off = 32; off >= 1; off >>= 1) {
        acc0 += __shfl_xor(acc0, off);
        acc1 += __shfl_xor(acc1, off);
        acc2 += __shfl_xor(acc2, off);
        acc3 += __shfl_xor(acc3, off);
    }

    if (lane == 0) {
        out[0 * N_RAY + ray] = acc0;
        out[1 * N_RAY + ray] = acc1;
        out[2 * N_RAY + ray] = acc2;
        out[3 * N_RAY + ray] = acc3;
    }
}

extern "C" void kernel_launch(void* const* d_in, const int* in_sizes, int n_in,
                              void* d_out, int out_size, void* d_ws, size_t ws_size,
                              hipStream_t stream) {
    const float* image = (const float*)d_in[0];
    const float* tvals = (const float*)d_in[1];
    const float* Mm    = (const float*)d_in[2];
    const float* bb    = (const float*)d_in[3];
    const float* src   = (const float*)d_in[4];
    const float* dst   = (const float*)d_in[5];
    float* out = (float*)d_out;

    if (ws_size >= WS_NEEDED) {
        float4* img_rc = (float4*)d_ws;
        float4* img_cr = img_rc + IMG_PIX;
        float*  part   = (float*)((char*)d_ws + WS_IMG);

        ct_prep_kernel<<<IMG_PIX / 256, 256, 0, stream>>>(image, img_rc, img_cr);
        ct_px_kernel<<<N_VIEW * NBAND, 256, 0, stream>>>(img_rc, img_cr, bb,
                                                         src, dst, part);
        dim3 rg(N_VIEW, 4);
        ct_reduce_kernel<<<rg, N_DET, 0, stream>>>(part, out);
    } else {
        ct_fwd_legacy<<<N_RAY / 4, 256, 0, stream>>>(image, tvals, Mm, bb,
                                                     src, dst, out);
    }
}

// Round 8
// 47.614 us; speedup vs baseline: 7.1444x; 7.1444x over previous
//
#include <hip/hip_runtime.h>

// Siddon forward projection, round 8: PIXEL-MATH, DETECTOR-GATHER.
// kf(r,c) = r*pxs + c*pys + C0 is affine; fast-axis coefficient >= 0.707,
// so for fixed (detector k, slow line s) at most 3 fast-pixels contribute.
// Thread = (view, detector); loops 16 slow lines, gathers 3 float4 pixels,
// accumulates trapezoid-chord weights in REGISTERS (no atomics at all).
// Band partials in d_ws; deterministic reduce kernel.
//
// inputs: image[4][256][256] f32, tvals (UNUSED), M[2][2] (=I), b[2],
//         src[69120][2], dst[69120][2]
// output: sinogram[4][69120] f32

#define N_ROW  256
#define N_COL  256
#define N_VIEW 180
#define N_DET  384
#define N_RAY  69120
#define IMG_PIX (N_ROW * N_COL)
#define NBAND  16
#define BANDH  (N_ROW / NBAND)     // 16 slow lines per band
#define PROF   (4 * N_DET)         // 1536 floats per partial profile
#define WS_IMG   (2u * IMG_PIX * 16u)                     // 2 MiB float4 x2
#define WS_PART  ((unsigned)(N_VIEW * NBAND * PROF) * 4u) // ~17.7 MiB
#define WS_NEEDED (WS_IMG + WS_PART)

__global__ __launch_bounds__(256) void ct_prep_kernel(
    const float* __restrict__ image,
    float4* __restrict__ img_rc,   // [r*256 + c] -> (ch0..ch3), c fastest
    float4* __restrict__ img_cr)   // [c*256 + r] -> (ch0..ch3), r fastest
{
    const int p = blockIdx.x * blockDim.x + threadIdx.x;
    if (p >= IMG_PIX) return;
    const int r = p >> 8;
    const int c = p & 255;
    float4 v;
    v.x = image[0 * IMG_PIX + p];
    v.y = image[1 * IMG_PIX + p];
    v.z = image[2 * IMG_PIX + p];
    v.w = image[3 * IMG_PIX + p];
    img_rc[p] = v;
    img_cr[(c << 8) | r] = v;
}

__global__ __launch_bounds__(384) void ct_gather_kernel(
    const float4* __restrict__ img_rc,
    const float4* __restrict__ img_cr,
    const float* __restrict__ bb,
    const float* __restrict__ src,
    const float* __restrict__ dst,
    float* __restrict__ part)      // [N_VIEW*NBAND][4][N_DET]
{
    const int wg   = blockIdx.x;
    const int v    = wg >> 4;          // / NBAND
    const int band = wg & (NBAND - 1);
    const int k    = threadIdx.x;      // detector 0..383

    // ---- per-view geometry, fp64, workgroup-uniform (validated round 7) ----
    const int r0 = v * N_DET;
    const double sx0 = (double)src[2 * r0 + 0], sy0 = (double)src[2 * r0 + 1];
    const double ex0 = (double)dst[2 * r0 + 0], ey0 = (double)dst[2 * r0 + 1];
    double gxd = ex0 - sx0, gyd = ey0 - sy0;
    const double gl = sqrt(gxd * gxd + gyd * gyd);
    gxd /= gl; gyd /= gl;                       // unit ray direction
    const double pxd = -gyd, pyd = gxd;         // unit perpendicular
    const double off0d = sx0 * pxd + sy0 * pyd; // detector-0 offset
    const double off1d = (double)src[2 * (r0 + 1) + 0] * pxd
                       + (double)src[2 * (r0 + 1) + 1] * pyd;
    const double sgn = (off1d > off0d) ? 1.0 : -1.0;   // spacing == 1 exactly

    const float pxs  = (float)(pxd * sgn);
    const float pys  = (float)(pyd * sgn);
    const float offs = (float)(off0d * sgn);

    const float a  = (float)fabs(gxd), b2 = (float)fabs(gyd);
    const float outer  = 0.5f * (a + b2);          // support half-width
    const float peak   = 1.0f / fmaxf(a, b2);      // plateau chord length
    const float inv_ab = 1.0f / fmaxf(a * b2, 1e-20f);

    const float bx = bb[0], by = bb[1];
    // kf = r*pxs + c*pys + C0
    const float C0 = bx * pxs + by * pys - offs;

    // fast axis = larger |coefficient| (>= 0.707): window <= 3 pixels
    const bool cfast = (fabsf(pys) >= fabsf(pxs));
    const float Fco = cfast ? pys : pxs;           // fast coefficient
    const float Sco = cfast ? pxs : pys;           // slow coefficient
    const float invF = 1.0f / Fco;
    const float hw   = outer * fabsf(invF);        // window half-width <= 1
    const float4* __restrict__ img = cfast ? img_rc : img_cr;

    float a0 = 0.f, a1 = 0.f, a2 = 0.f, a3 = 0.f;

    #pragma unroll 4
    for (int it = 0; it < BANDH; ++it) {
        const int s = band * BANDH + it;           // slow line
        const float T  = (float)k - fmaf(Sco, (float)s, C0);  // target: Fco*c = T
        const float cs = T * invF;                 // window center
        const float cbf = ceilf(cs - hw);
        const int   cb  = (int)cbf;

        #pragma unroll
        for (int j = 0; j < 3; ++j) {
            const int   cj = cb + j;
            const float e  = fmaf(Fco, (float)cj, -T);   // kf - k
            float w = fminf(fmaxf((outer - fabsf(e)) * inv_ab, 0.0f), peak);
            if ((unsigned)cj >= 256u) w = 0.0f;
            const int cc  = min(max(cj, 0), 255);
            const float4 vv = img[(s << 8) | cc];
            a0 = fmaf(w, vv.x, a0);
            a1 = fmaf(w, vv.y, a1);
            a2 = fmaf(w, vv.z, a2);
            a3 = fmaf(w, vv.w, a3);
        }
    }

    float* __restrict__ dp = part + (long)wg * PROF;
    dp[0 * N_DET + k] = a0;
    dp[1 * N_DET + k] = a1;
    dp[2 * N_DET + k] = a2;
    dp[3 * N_DET + k] = a3;
}

__global__ __launch_bounds__(384) void ct_reduce_kernel(
    const float* __restrict__ part,
    float* __restrict__ out)
{
    const int v  = blockIdx.x;       // 0..179
    const int ch = blockIdx.y;       // 0..3
    const int k  = threadIdx.x;      // 0..383
    float s = 0.0f;
    #pragma unroll
    for (int b = 0; b < NBAND; ++b)
        s += part[(long)(v * NBAND + b) * PROF + ch * N_DET + k];
    out[ch * N_RAY + v * N_DET + k] = s;
}

// ---- legacy fallback (round-1 kernel) if ws is too small ----
__global__ __launch_bounds__(256) void ct_fwd_legacy(
    const float* __restrict__ image,
    const float* __restrict__ tvals,
    const float* __restrict__ Mm,
    const float* __restrict__ bb,
    const float* __restrict__ src,
    const float* __restrict__ dst,
    float* __restrict__ out)
{
    const int wave = (blockIdx.x * blockDim.x + threadIdx.x) >> 6;
    const int lane = threadIdx.x & 63;
    if (wave >= N_RAY) return;
    const int ray = wave;

    const float m00 = Mm[0], m01 = Mm[1], m10 = Mm[2], m11 = Mm[3];
    const float invdet = 1.0f / (m00 * m11 - m01 * m10);
    const float i00 =  m11 * invdet, i01 = -m01 * invdet;
    const float i10 = -m10 * invdet, i11 =  m00 * invdet;

    const float sx = src[ray * 2 + 0], sy = src[ray * 2 + 1];
    const float ex = dst[ray * 2 + 0], ey = dst[ray * 2 + 1];
    const float bx = bb[0], by = bb[1];

    const float p0x = i00 * (sx - bx) + i01 * (sy - by);
    const float p0y = i10 * (sx - bx) + i11 * (sy - by);
    const float wdx = ex - sx, wdy = ey - sy;
    const float dx = i00 * wdx + i01 * wdy;
    const float dy = i10 * wdx + i11 * wdy;
    const float ray_len = sqrtf(wdx * wdx + wdy * wdy);

    const float* __restrict__ tv  = tvals + (long)ray * 514;
    const float* __restrict__ im0 = image;
    const float* __restrict__ im1 = image + 1 * IMG_PIX;
    const float* __restrict__ im2 = image + 2 * IMG_PIX;
    const float* __restrict__ im3 = image + 3 * IMG_PIX;

    float acc0 = 0.f, acc1 = 0.f, acc2 = 0.f, acc3 = 0.f;

    #pragma unroll
    for (int i = 0; i < 9; ++i) {
        const int s = i * 64 + lane;
        if (s < 513) {
            const float t0 = tv[s];
            const float t1 = tv[s + 1];
            const float dt = t1 - t0;
            if (dt > 0.f) {
                const float tm = 0.5f * (t0 + t1);
                const float ux = fmaf(tm, dx, p0x);
                const float uy = fmaf(tm, dy, p0y);
                const float rf = floorf(ux + 0.5f);
                const float cf = floorf(uy + 0.5f);
                if (rf >= 0.f && rf < (float)N_ROW && cf >= 0.f && cf < (float)N_COL) {
                    const int idx = (int)rf * N_COL + (int)cf;
                    const float w = dt * ray_len;
                    acc0 = fmaf(w, im0[idx], acc0);
                    acc1 = fmaf(w, im1[idx], acc1);
                    acc2 = fmaf(w, im2[idx], acc2);
                    acc3 = fmaf(w, im3[idx], acc3);
                }
            }
        }
    }

    #pragma unroll
    for (int off = 32; off >= 1; off >>= 1) {
        acc0 += __shfl_xor(acc0, off);
        acc1 += __shfl_xor(acc1, off);
        acc2 += __shfl_xor(acc2, off);
        acc3 += __shfl_xor(acc3, off);
    }

    if (lane == 0) {
        out[0 * N_RAY + ray] = acc0;
        out[1 * N_RAY + ray] = acc1;
        out[2 * N_RAY + ray] = acc2;
        out[3 * N_RAY + ray] = acc3;
    }
}

extern "C" void kernel_launch(void* const* d_in, const int* in_sizes, int n_in,
                              void* d_out, int out_size, void* d_ws, size_t ws_size,
                              hipStream_t stream) {
    const float* image = (const float*)d_in[0];
    const float* tvals = (const float*)d_in[1];
    const float* Mm    = (const float*)d_in[2];
    const float* bb    = (const float*)d_in[3];
    const float* src   = (const float*)d_in[4];
    const float* dst   = (const float*)d_in[5];
    float* out = (float*)d_out;

    if (ws_size >= WS_NEEDED) {
        float4* img_rc = (float4*)d_ws;
        float4* img_cr = img_rc + IMG_PIX;
        float*  part   = (float*)((char*)d_ws + WS_IMG);

        ct_prep_kernel<<<IMG_PIX / 256, 256, 0, stream>>>(image, img_rc, img_cr);
        ct_gather_kernel<<<N_VIEW * NBAND, N_DET, 0, stream>>>(img_rc, img_cr,
                                                               bb, src, dst, part);
        dim3 rg(N_VIEW, 4);
        ct_reduce_kernel<<<rg, N_DET, 0, stream>>>(part, out);
    } else {
        ct_fwd_legacy<<<N_RAY / 4, 256, 0, stream>>>(image, tvals, Mm, bb,
                                                     src, dst, out);
    }
}